// Round 1
// baseline (195.424 us; speedup 1.0000x reference)
//
#include <hip/hip_runtime.h>

// Problem constants (fixed by setup_inputs): B=128, BANDS=256, P=32, K=64
#define SIGMA 0.1f
#define BANDS 256
#define KSEL  64

// Kernel 1: compute gates, select top-64 (jax.lax.top_k tie-break: lower
// index wins on equal values), emit indices sorted ascending + gathered gate
// values into workspace.
__global__ void FeatureSelector_topk(const float* __restrict__ mu,
                                     const float* __restrict__ noise,
                                     const float* __restrict__ extra,
                                     int*   __restrict__ ws_idx,
                                     float* __restrict__ ws_gate) {
    __shared__ float g[BANDS];
    __shared__ int   sel[BANDS];
    const int tid = threadIdx.x;

    float z = mu[tid] + SIGMA * (noise[tid] + 0.25f * extra[tid]) + 0.5f;
    float gate = fminf(fmaxf(z, 0.0f), 1.0f);
    g[tid] = gate;
    __syncthreads();

    // rank = number of elements that beat me (higher value, or equal value
    // with lower index). rank < K  =>  selected.
    int rank = 0;
    for (int j = 0; j < BANDS; ++j) {
        float gj = g[j];
        rank += (gj > gate) || (gj == gate && j < tid);
    }
    sel[tid] = (rank < KSEL) ? 1 : 0;
    __syncthreads();

    if (rank < KSEL) {
        // position among selected, in ascending index order (== jnp.sort(idx))
        int pos = 0;
        for (int j = 0; j < tid; ++j) pos += sel[j];
        ws_idx[pos]  = tid;
        ws_gate[pos] = gate;
    }
}

// Kernel 2: out[b, j, :, :] = x[b, idx[j], :, :] * gate[idx[j]]
// One block per (b, j); 256 threads x float4 = 1024 floats = one 32x32 plane.
__global__ void FeatureSelector_gather(const float4* __restrict__ x,
                                       const int*    __restrict__ ws_idx,
                                       const float*  __restrict__ ws_gate,
                                       float4*       __restrict__ out) {
    const int bj = blockIdx.x;
    const int b  = bj >> 6;       // / KSEL
    const int j  = bj & (KSEL - 1);
    const int band = ws_idx[j];
    const float s  = ws_gate[j];
    const int tid = threadIdx.x;

    float4 v = x[(b * BANDS + band) * 256 + tid];
    v.x *= s; v.y *= s; v.z *= s; v.w *= s;
    out[(b * KSEL + j) * 256 + tid] = v;
}

extern "C" void kernel_launch(void* const* d_in, const int* in_sizes, int n_in,
                              void* d_out, int out_size, void* d_ws, size_t ws_size,
                              hipStream_t stream) {
    const float* x     = (const float*)d_in[0];  // (128,1,256,32,32)
    const float* mu    = (const float*)d_in[1];  // (256,)
    const float* noise = (const float*)d_in[2];  // (256,)
    const float* extra = (const float*)d_in[3];  // (256,)
    // d_in[4] = k (=64), hard-coded as KSEL

    int*   ws_idx  = (int*)d_ws;
    float* ws_gate = (float*)((char*)d_ws + KSEL * sizeof(int));

    FeatureSelector_topk<<<1, BANDS, 0, stream>>>(mu, noise, extra, ws_idx, ws_gate);

    const int B = 128;
    FeatureSelector_gather<<<B * KSEL, 256, 0, stream>>>(
        (const float4*)x, ws_idx, ws_gate, (float4*)d_out);
}

// Round 2
// 193.666 us; speedup vs baseline: 1.0091x; 1.0091x over previous
//
#include <hip/hip_runtime.h>

// Problem constants (fixed by setup_inputs): B=128, BANDS=256, P=32, K=64
#define SIGMA 0.1f
#define BANDS 256
#define KSEL  64

// Kernel 1: compute gates, select top-64 (jax.lax.top_k tie-break: lower
// index wins on equal values), emit indices sorted ascending + gathered gate
// values into workspace. Ballot-based prefix (no O(tid) serial loop).
__global__ void FeatureSelector_topk(const float* __restrict__ mu,
                                     const float* __restrict__ noise,
                                     const float* __restrict__ extra,
                                     int*   __restrict__ ws_idx,
                                     float* __restrict__ ws_gate) {
    __shared__ float g[BANDS];
    __shared__ unsigned long long masks[BANDS / 64];
    const int tid  = threadIdx.x;
    const int wave = tid >> 6;
    const int lane = tid & 63;

    float z = mu[tid] + SIGMA * (noise[tid] + 0.25f * extra[tid]) + 0.5f;
    float gate = fminf(fmaxf(z, 0.0f), 1.0f);
    g[tid] = gate;
    __syncthreads();

    // rank = number of elements that beat me (higher value, or equal value
    // with lower index). rank < K  =>  selected.
    int rank = 0;
#pragma unroll 8
    for (int j = 0; j < BANDS; ++j) {
        float gj = g[j];
        rank += (gj > gate) || (gj == gate && j < tid);
    }
    const bool sel = rank < KSEL;

    unsigned long long m = __ballot(sel);
    if (lane == 0) masks[wave] = m;
    __syncthreads();

    if (sel) {
        // position among selected, ascending index order (== jnp.sort(idx))
        int pos = __popcll(m & ((1ull << lane) - 1ull));
        for (int w = 0; w < wave; ++w) pos += __popcll(masks[w]);
        ws_idx[pos]  = tid;
        ws_gate[pos] = gate;
    }
}

// Kernel 2: out[b, j, :, :] = x[b, idx[j], :, :] * gate[idx[j]]
// One block per 2 consecutive (b, j) pairs; 256 threads x 2 float4.
__global__ void FeatureSelector_gather(const float4* __restrict__ x,
                                       const int*    __restrict__ ws_idx,
                                       const float*  __restrict__ ws_gate,
                                       float4*       __restrict__ out) {
    const int pair = blockIdx.x;          // 0 .. B*KSEL/2 - 1
    const int bj0  = pair << 1;           // even, so both planes share b
    const int b    = bj0 >> 6;            // / KSEL
    const int j0   = bj0 & (KSEL - 1);
    const int tid  = threadIdx.x;

    const int   band0 = ws_idx[j0];
    const int   band1 = ws_idx[j0 + 1];
    const float s0    = ws_gate[j0];
    const float s1    = ws_gate[j0 + 1];

    float4 v0 = x[(b * BANDS + band0) * 256 + tid];
    float4 v1 = x[(b * BANDS + band1) * 256 + tid];
    v0.x *= s0; v0.y *= s0; v0.z *= s0; v0.w *= s0;
    v1.x *= s1; v1.y *= s1; v1.z *= s1; v1.w *= s1;
    out[(b * KSEL + j0) * 256 + tid]     = v0;
    out[(b * KSEL + j0 + 1) * 256 + tid] = v1;
}

extern "C" void kernel_launch(void* const* d_in, const int* in_sizes, int n_in,
                              void* d_out, int out_size, void* d_ws, size_t ws_size,
                              hipStream_t stream) {
    const float* x     = (const float*)d_in[0];  // (128,1,256,32,32)
    const float* mu    = (const float*)d_in[1];  // (256,)
    const float* noise = (const float*)d_in[2];  // (256,)
    const float* extra = (const float*)d_in[3];  // (256,)
    // d_in[4] = k (=64), hard-coded as KSEL

    int*   ws_idx  = (int*)d_ws;
    float* ws_gate = (float*)((char*)d_ws + KSEL * sizeof(int));

    FeatureSelector_topk<<<1, BANDS, 0, stream>>>(mu, noise, extra, ws_idx, ws_gate);

    const int B = 128;
    FeatureSelector_gather<<<(B * KSEL) / 2, 256, 0, stream>>>(
        (const float4*)x, ws_idx, ws_gate, (float4*)d_out);
}